// Round 1
// baseline (2414.984 us; speedup 1.0000x reference)
//
#include <hip/hip_runtime.h>
#include <math.h>

// Problem constants (B=2, T=2048, DIM=2048, HEADS=16, HEAD_DIM=128, N_KV=4,
// LATENT=512, SEL_TOPK=64, SEL_DIM=64, SOFTCAP=30, EPS=1e-6)
#define T_SEQ 2048
#define BATCH 2
#define NHEADS 16
#define HD 128
#define NKV 4

// ---------------------------------------------------------------------------
// RoPE table: tab[t][i] = (cos, sin) of angle_i(t), i = pair index 0..63.
// Mimic numpy fp32 op order: y=fl32(10000^x) (double pow, rounded), inv=1/y
// (fp32 divide), angle = fl32(t * inv), cos/sin correctly rounded via double.
// freq index j = (2i) mod 64  (emb = concat([f, f]) then [0::2] slicing).
// ---------------------------------------------------------------------------
__global__ void rope_table_kernel(float* __restrict__ tab) {
  int t = blockIdx.x;
  int i = threadIdx.x;                 // 0..63
  int j = (2 * i) & 63;
  float y = (float)pow(10000.0, (double)j / 64.0);
  float invf = 1.0f / y;
  float angle = (float)t * invf;
  double a = (double)angle;
  tab[(t * 64 + i) * 2 + 0] = (float)cos(a);
  tab[(t * 64 + i) * 2 + 1] = (float)sin(a);
}

// ---------------------------------------------------------------------------
// RMSNorm (over 128 dims) + interleaved RoPE, in place.
// base layout: (b*T) groups of rowStride floats, head h at offset h*128.
// ---------------------------------------------------------------------------
__global__ __launch_bounds__(128) void norm_rope_kernel(
    float* __restrict__ base, const float* __restrict__ w,
    const float* __restrict__ tab, int Hloc, int rowStride) {
  int blk = blockIdx.x;
  int h = blk % Hloc;
  int bt = blk / Hloc;
  int t = bt & (T_SEQ - 1);
  float* row = base + (size_t)bt * rowStride + h * HD;
  int d = threadIdx.x;
  float v = row[d];
  __shared__ float red[128];
  red[d] = v * v;
  __syncthreads();
#pragma unroll
  for (int off = 64; off > 0; off >>= 1) {
    if (d < off) red[d] += red[d + off];
    __syncthreads();
  }
  float ssum = red[0];
  __syncthreads();
  float inv = 1.0f / sqrtf(ssum / 128.0f + 1e-6f);
  float xn = v * inv * w[d];
  red[d] = xn;
  __syncthreads();
  int p = d >> 1;
  float c  = tab[(t * 64 + p) * 2 + 0];
  float sn = tab[(t * 64 + p) * 2 + 1];
  float x1 = red[p * 2], x2 = red[p * 2 + 1];
  row[d] = ((d & 1) == 0) ? (x1 * c - x2 * sn) : (x1 * sn + x2 * c);
}

// ---------------------------------------------------------------------------
// fp32 tiled GEMM: C[M,N] = A[M,K] @ W[K,N] + bias[N]
// 64x64 tile, BK=16, 256 threads, 4x4 microtile. All dims multiples required.
// ---------------------------------------------------------------------------
#define BKG 16
__global__ __launch_bounds__(256) void sgemm_kernel(
    const float* __restrict__ A, const float* __restrict__ W,
    const float* __restrict__ bias, float* __restrict__ C,
    int M, int N, int K) {
  __shared__ float As[BKG][68];   // [k][m], padded
  __shared__ float Bs[BKG][68];   // [k][n], padded (68 keeps 16B alignment)
  int tid = threadIdx.x;
  int tx = tid & 15;              // n group (4 cols)
  int ty = tid >> 4;              // m group (4 rows)
  int m0 = blockIdx.y * 64;
  int n0 = blockIdx.x * 64;
  int ar = tid >> 2, ac = (tid & 3) * 4;
  int brr = tid >> 4, bc = (tid & 15) * 4;
  const float* Ap = A + (size_t)(m0 + ar) * K + ac;
  const float* Wp = W + (size_t)brr * N + n0 + bc;
  float acc[4][4] = {};
  for (int k0 = 0; k0 < K; k0 += BKG) {
    float4 av = *(const float4*)(Ap + k0);
    float4 wv = *(const float4*)(Wp + (size_t)k0 * N);
    As[ac + 0][ar] = av.x; As[ac + 1][ar] = av.y;
    As[ac + 2][ar] = av.z; As[ac + 3][ar] = av.w;
    *(float4*)&Bs[brr][bc] = wv;
    __syncthreads();
#pragma unroll
    for (int kk = 0; kk < BKG; kk++) {
      float4 a = *(const float4*)&As[kk][ty * 4];
      float4 b = *(const float4*)&Bs[kk][tx * 4];
      float aa[4] = {a.x, a.y, a.z, a.w};
      float bb[4] = {b.x, b.y, b.z, b.w};
#pragma unroll
      for (int i = 0; i < 4; i++)
#pragma unroll
        for (int j = 0; j < 4; j++) acc[i][j] += aa[i] * bb[j];
    }
    __syncthreads();
  }
  float4 bv = *(const float4*)&bias[n0 + tx * 4];
  float bb[4] = {bv.x, bv.y, bv.z, bv.w};
#pragma unroll
  for (int i = 0; i < 4; i++) {
    float4 o;
    o.x = acc[i][0] + bb[0];
    o.y = acc[i][1] + bb[1];
    o.z = acc[i][2] + bb[2];
    o.w = acc[i][3] + bb[3];
    *(float4*)&C[(size_t)(m0 + ty * 4 + i) * N + n0 + tx * 4] = o;
  }
}

// ---------------------------------------------------------------------------
// Selection: per (b,row) compute head-0 scores (first 64 dims, /8, causal)
// and take top-64 (stable: larger value, then smaller index — matches
// jax.lax.top_k) ∪ {diag}. Emits index list + count per row.
// Block = 4 consecutive rows. Rows < 64: all causal keys selected.
// ---------------------------------------------------------------------------
__device__ inline unsigned long long sel_encode(float v, int c) {
  unsigned u = __float_as_uint(v);
  u = (u & 0x80000000u) ? ~u : (u | 0x80000000u);
  return ((unsigned long long)u << 32) | (unsigned)(0xFFFFFFFFu - (unsigned)c);
}

__global__ __launch_bounds__(256) void select_topk_kernel(
    const float* __restrict__ q, const float* __restrict__ kv,
    int* __restrict__ sel_cnt, int* __restrict__ sel_idx) {
  int blk = blockIdx.x;            // B*T/4 blocks
  int b = blk >> 9;
  int r0 = (blk & 511) * 4;
  int tid = threadIdx.x;

  if (r0 < 64) {                   // rows 0..63: everything causal selected
    for (int j = 0; j < 4; j++) {
      int r = r0 + j;
      int row = b * T_SEQ + r;
      if (tid == 0) sel_cnt[row] = r + 1;
      for (int c = tid; c <= r; c += 256) sel_idx[row * 66 + c] = c;
    }
    return;
  }

  __shared__ float qs[4][64];
  __shared__ float sc[4][2048];
  __shared__ unsigned long long wred[4];
  __shared__ int winners[66];
  __shared__ int hasdiag;

  {
    int i = tid;                    // 4*64 = 256 exactly
    int j = i >> 6, d = i & 63;
    qs[j][d] = q[((size_t)(b * T_SEQ + r0 + j) * NHEADS + 0) * HD + d];
  }
  __syncthreads();

  // scores: thread owns columns c = tid + 256k
  for (int k8 = 0; k8 < 8; k8++) {
    int c = tid + 256 * k8;
    const float* kp = kv + (size_t)(b * T_SEQ + c) * 1024;  // k head 0
    float kreg[64];
#pragma unroll
    for (int i = 0; i < 16; i++)
      *(float4*)&kreg[i * 4] = *(const float4*)(kp + i * 4);
#pragma unroll
    for (int j = 0; j < 4; j++) {
      float acc = 0.f;
#pragma unroll
      for (int d = 0; d < 64; d++) acc += qs[j][d] * kreg[d];
      sc[j][c] = (c <= r0 + j) ? acc * 0.125f : -INFINITY;
    }
  }
  __syncthreads();

  int lane = tid & 63, wvid = tid >> 6;

  for (int j = 0; j < 4; j++) {
    int r = r0 + j;
    unsigned long long lbest = 0ull;
#pragma unroll
    for (int k8 = 0; k8 < 8; k8++) {
      int c = tid + 256 * k8;
      unsigned long long e = sel_encode(sc[j][c], c);
      lbest = lbest > e ? lbest : e;
    }
    for (int it = 0; it < 64; it++) {
      unsigned long long wb = lbest;
#pragma unroll
      for (int off = 32; off > 0; off >>= 1) {
        unsigned long long o = __shfl_down(wb, off);
        wb = wb > o ? wb : o;
      }
      if (lane == 0) wred[wvid] = wb;
      __syncthreads();
      unsigned long long g01 = wred[0] > wred[1] ? wred[0] : wred[1];
      unsigned long long g23 = wred[2] > wred[3] ? wred[2] : wred[3];
      unsigned long long gbb = g01 > g23 ? g01 : g23;
      int c = (int)(0xFFFFFFFFu - (unsigned)(gbb & 0xFFFFFFFFull));
      if (tid == 0) winners[it] = c;
      if (tid == (c & 255)) {        // owner invalidates + rescans
        sc[j][c] = -INFINITY;
        unsigned long long nb = 0ull;
#pragma unroll
        for (int k8 = 0; k8 < 8; k8++) {
          int cc = tid + 256 * k8;
          unsigned long long e = sel_encode(sc[j][cc], cc);
          nb = nb > e ? nb : e;
        }
        lbest = nb;
      }
      __syncthreads();
    }
    if (tid == 0) hasdiag = 0;
    __syncthreads();
    if (tid < 64 && winners[tid] == r) hasdiag = 1;
    __syncthreads();
    int cnt = 64;
    if (!hasdiag) { cnt = 65; if (tid == 0) winners[64] = r; }
    __syncthreads();
    int row = b * T_SEQ + r;
    if (tid == 0) sel_cnt[row] = cnt;
    if (tid < cnt) sel_idx[row * 66 + tid] = winners[tid];
    __syncthreads();
  }
}

// ---------------------------------------------------------------------------
// Gathered attention: block = (b, r, kv-group g); wave wv = local head.
// K gathered transposed to LDS (stride 67 => conflict-free score reads),
// V streamed coalesced from global (L2-hot). Softcap + ALiBi + softmax + PV.
// Writes pre-gate y into yg (b, t, h*128+d).
// ---------------------------------------------------------------------------
__global__ __launch_bounds__(256) void attn_kernel(
    const float* __restrict__ q, const float* __restrict__ kv,
    const int* __restrict__ sel_cnt, const int* __restrict__ sel_idx,
    float* __restrict__ yg) {
  int blk = blockIdx.x;
  int g = blk & 3;
  int br = blk >> 2;               // b*T + r
  int b = br >> 11;
  int r = br & (T_SEQ - 1);
  int tid = threadIdx.x;
  int lane = tid & 63, wv = tid >> 6;

  __shared__ float ksT[128][67];   // [d][j]
  __shared__ float qsh[4][128];
  __shared__ int idxs[66];

  int cnt = sel_cnt[br];
  if (tid < cnt) idxs[tid] = sel_idx[br * 66 + tid];
  for (int i = tid; i < 4 * 128; i += 256) {
    int h = i >> 7, d = i & 127;
    qsh[h][d] = q[((size_t)br * NHEADS + g * 4 + h) * HD + d];
  }
  __syncthreads();
  for (int i = tid; i < cnt * 32; i += 256) {
    int j = i >> 5, d4 = (i & 31) * 4;
    const float* kp = kv + (size_t)(b * T_SEQ + idxs[j]) * 1024 + g * HD + d4;
    float4 kd = *(const float4*)kp;
    ksT[d4 + 0][j] = kd.x; ksT[d4 + 1][j] = kd.y;
    ksT[d4 + 2][j] = kd.z; ksT[d4 + 3][j] = kd.w;
  }
  __syncthreads();

  int H = g * 4 + wv;
  // alibi slope = (2^-0.5)^(H+1), double repeated-multiply then fp32 round
  double sd = 1.0;
  for (int i = 0; i <= H; i++) sd *= 0.70710678118654752440;
  float slope = (float)sd;

  float s0 = -INFINITY, s1 = -INFINITY;
  for (int jj = lane; jj < cnt; jj += 64) {
    float acc = 0.f;
#pragma unroll 8
    for (int d = 0; d < 128; d++) acc += qsh[wv][d] * ksT[d][jj];
    float sca = acc / sqrtf(128.0f);
    float tch = tanhf(sca / 30.0f) * 30.0f;
    float biasv = -slope * (float)(r - idxs[jj]);
    float val = tch + biasv;
    if (jj == lane) s0 = val; else s1 = val;
  }
  float m = fmaxf(s0, s1);
#pragma unroll
  for (int off = 32; off > 0; off >>= 1) m = fmaxf(m, __shfl_down(m, off));
  m = __shfl(m, 0);
  float e0 = (lane < cnt) ? expf(s0 - m) : 0.f;
  float e1 = (lane + 64 < cnt) ? expf(s1 - m) : 0.f;
  float sum = e0 + e1;
#pragma unroll
  for (int off = 32; off > 0; off >>= 1) sum += __shfl_down(sum, off);
  sum = __shfl(sum, 0);
  float p0 = e0 / sum;
  float p1 = e1 / sum;

  const float* vbase = kv + (size_t)b * T_SEQ * 1024 + 512 + g * HD;
  float y0 = 0.f, y1 = 0.f;
  for (int j = 0; j < cnt; j++) {
    float pj = (j < 64) ? __shfl(p0, j) : __shfl(p1, j - 64);
    const float* vp = vbase + (size_t)idxs[j] * 1024;
    y0 += pj * vp[lane];
    y1 += pj * vp[lane + 64];
  }
  float* op = yg + (size_t)br * 2048 + H * HD;
  op[lane] = y0;
  op[lane + 64] = y1;
}

// ---------------------------------------------------------------------------
// Gate: y *= sigmoid(y @ gate_w[h] + gate_b[h]), in place on yg.
// Block = (16-row tile, head). gate_w streamed coalesced from global (L2).
// ---------------------------------------------------------------------------
__global__ __launch_bounds__(256) void gate_kernel(
    float* __restrict__ yg, const float* __restrict__ gw,
    const float* __restrict__ gb) {
  int blk = blockIdx.x;            // bt16*16 + h
  int h = blk & 15;
  int bt0 = (blk >> 4) * 16;
  int tid = threadIdx.x;
  __shared__ float ys[16][128];
  for (int i = tid; i < 16 * 128; i += 256) {
    int rr = i >> 7, d = i & 127;
    ys[rr][d] = yg[(size_t)(bt0 + rr) * 2048 + h * HD + d];
  }
  __syncthreads();
  int e = tid & 127;
  int rblk = tid >> 7;
  const float* gwp = gw + (size_t)h * 16384 + e;
  float acc[8] = {};
  for (int d = 0; d < 128; d++) {
    float wval = gwp[(size_t)d * 128];
#pragma unroll
    for (int k = 0; k < 8; k++) acc[k] += ys[rblk * 8 + k][d] * wval;
  }
  float bb = gb[h * 128 + e];
#pragma unroll
  for (int k = 0; k < 8; k++) {
    int rr = rblk * 8 + k;
    float gate = 1.f / (1.f + expf(-(acc[k] + bb)));
    yg[(size_t)(bt0 + rr) * 2048 + h * HD + e] = ys[rr][e] * gate;
  }
}

// ---------------------------------------------------------------------------
extern "C" void kernel_launch(void* const* d_in, const int* in_sizes, int n_in,
                              void* d_out, int out_size, void* d_ws, size_t ws_size,
                              hipStream_t stream) {
  const float* x      = (const float*)d_in[0];
  const float* w_q    = (const float*)d_in[1];
  const float* b_q    = (const float*)d_in[2];
  const float* w_down = (const float*)d_in[3];
  const float* b_down = (const float*)d_in[4];
  const float* w_up   = (const float*)d_in[5];
  const float* b_up   = (const float*)d_in[6];
  const float* w_o    = (const float*)d_in[7];
  const float* b_o    = (const float*)d_in[8];
  const float* qn_w   = (const float*)d_in[9];
  const float* kn_w   = (const float*)d_in[10];
  const float* gate_w = (const float*)d_in[11];
  const float* gate_b = (const float*)d_in[12];

  // ws layout (floats): kv 4.19M | yg 8.39M (dlat overlaps head of yg) |
  // rope tab 0.26M | sel_cnt 4096 ints | sel_idx 4096*66 ints  (~53 MB)
  float* ws    = (float*)d_ws;
  float* kvbuf = ws;
  float* yg    = ws + 4194304;
  float* dlat  = yg;                        // dead before attn writes yg
  float* tab   = ws + 4194304 + 8388608;
  int*   cnt   = (int*)(tab + 262144);
  int*   sidx  = cnt + 4096;

  float* qbuf = (float*)d_out;              // d_out doubles as q staging

  const int BT = BATCH * T_SEQ;             // 4096

  rope_table_kernel<<<T_SEQ, 64, 0, stream>>>(tab);
  // q = x @ w_q + b_q   (into d_out)
  sgemm_kernel<<<dim3(2048 / 64, BT / 64), 256, 0, stream>>>(
      x, w_q, b_q, qbuf, BT, 2048, 2048);
  // dlat = x @ w_down + b_down
  sgemm_kernel<<<dim3(512 / 64, BT / 64), 256, 0, stream>>>(
      x, w_down, b_down, dlat, BT, 512, 2048);
  // kv = dlat @ w_up + b_up
  sgemm_kernel<<<dim3(1024 / 64, BT / 64), 256, 0, stream>>>(
      dlat, w_up, b_up, kvbuf, BT, 1024, 512);
  // rmsnorm + rope
  norm_rope_kernel<<<BT * 16, 128, 0, stream>>>(qbuf, qn_w, tab, 16, 2048);
  norm_rope_kernel<<<BT * 4, 128, 0, stream>>>(kvbuf, kn_w, tab, 4, 1024);
  // top-64 selection (head 0, first 64 dims)
  select_topk_kernel<<<BT / 4, 256, 0, stream>>>(qbuf, kvbuf, cnt, sidx);
  // gathered sparse attention -> yg (pre-gate)
  attn_kernel<<<BT * 4, 256, 0, stream>>>(qbuf, kvbuf, cnt, sidx, yg);
  // per-head gating, in place
  gate_kernel<<<(BT / 16) * 16, 256, 0, stream>>>(yg, gate_w, gate_b);
  // out = yg @ w_o + b_o
  sgemm_kernel<<<dim3(2048 / 64, BT / 64), 256, 0, stream>>>(
      yg, w_o, b_o, (float*)d_out, BT, 2048, 2048);
}

// Round 2
// 1399.221 us; speedup vs baseline: 1.7259x; 1.7259x over previous
//
#include <hip/hip_runtime.h>
#include <math.h>

// Problem constants (B=2, T=2048, DIM=2048, HEADS=16, HEAD_DIM=128, N_KV=4,
// LATENT=512, SEL_TOPK=64, SEL_DIM=64, SOFTCAP=30, EPS=1e-6)
#define T_SEQ 2048
#define BATCH 2
#define NHEADS 16
#define HD 128
#define NKV 4

typedef __bf16 bf16x8 __attribute__((ext_vector_type(8)));
typedef float f32x4 __attribute__((ext_vector_type(4)));

__device__ inline unsigned short bf16rne(float f) {
  unsigned u = __float_as_uint(f);
  unsigned r = (u + 0x7FFFu + ((u >> 16) & 1u)) >> 16;
  return (unsigned short)r;
}

__device__ inline void gload_lds16(const void* g, void* l) {
  __builtin_amdgcn_global_load_lds(
      (__attribute__((address_space(1))) void*)const_cast<void*>(g),
      (__attribute__((address_space(3))) void*)l, 16, 0, 0);
}

// ---------------------------------------------------------------------------
// RoPE table: tab[t][i] = (cos, sin), i = pair index 0..63. numpy fp32 op
// order: y=fl32(10000^x) (double pow), inv=1/y (fp32), angle=fl32(t*inv).
// ---------------------------------------------------------------------------
__global__ void rope_table_kernel(float* __restrict__ tab) {
  int t = blockIdx.x;
  int i = threadIdx.x;                 // 0..63
  int j = (2 * i) & 63;
  float y = (float)pow(10000.0, (double)j / 64.0);
  float invf = 1.0f / y;
  float angle = (float)t * invf;
  double a = (double)angle;
  tab[(t * 64 + i) * 2 + 0] = (float)cos(a);
  tab[(t * 64 + i) * 2 + 1] = (float)sin(a);
}

// ---------------------------------------------------------------------------
// RMSNorm (128 dims) + interleaved RoPE, in place.
// ---------------------------------------------------------------------------
__global__ __launch_bounds__(128) void norm_rope_kernel(
    float* __restrict__ base, const float* __restrict__ w,
    const float* __restrict__ tab, int Hloc, int rowStride) {
  int blk = blockIdx.x;
  int h = blk % Hloc;
  int bt = blk / Hloc;
  int t = bt & (T_SEQ - 1);
  float* row = base + (size_t)bt * rowStride + h * HD;
  int d = threadIdx.x;
  float v = row[d];
  __shared__ float red[128];
  red[d] = v * v;
  __syncthreads();
#pragma unroll
  for (int off = 64; off > 0; off >>= 1) {
    if (d < off) red[d] += red[d + off];
    __syncthreads();
  }
  float ssum = red[0];
  __syncthreads();
  float inv = 1.0f / sqrtf(ssum / 128.0f + 1e-6f);
  float xn = v * inv * w[d];
  red[d] = xn;
  __syncthreads();
  int p = d >> 1;
  float c  = tab[(t * 64 + p) * 2 + 0];
  float sn = tab[(t * 64 + p) * 2 + 1];
  float x1 = red[p * 2], x2 = red[p * 2 + 1];
  row[d] = ((d & 1) == 0) ? (x1 * c - x2 * sn) : (x1 * sn + x2 * c);
}

// ---------------------------------------------------------------------------
// fp32 tiled GEMM (kept ONLY for the exact selection path + latent projs):
// C[M,N] = A[M,K] @ W[K,N] + bias.  64x64 tile, BK=16, 4x4 microtile.
// ldw = W row stride, ldc = C row stride. K-summation order is sequential
// over k (bit-identical to round 1 -> selection indices unchanged).
// ---------------------------------------------------------------------------
#define BKG 16
__global__ __launch_bounds__(256) void sgemm_kernel(
    const float* __restrict__ A, const float* __restrict__ W,
    const float* __restrict__ bias, float* __restrict__ C,
    int M, int N, int K, int ldw, int ldc) {
  __shared__ float As[BKG][68];
  __shared__ float Bs[BKG][68];
  int tid = threadIdx.x;
  int tx = tid & 15;
  int ty = tid >> 4;
  int m0 = blockIdx.y * 64;
  int n0 = blockIdx.x * 64;
  int ar = tid >> 2, ac = (tid & 3) * 4;
  int brr = tid >> 4, bc = (tid & 15) * 4;
  const float* Ap = A + (size_t)(m0 + ar) * K + ac;
  const float* Wp = W + (size_t)brr * ldw + n0 + bc;
  float acc[4][4] = {};
  for (int k0 = 0; k0 < K; k0 += BKG) {
    float4 av = *(const float4*)(Ap + k0);
    float4 wv = *(const float4*)(Wp + (size_t)k0 * ldw);
    As[ac + 0][ar] = av.x; As[ac + 1][ar] = av.y;
    As[ac + 2][ar] = av.z; As[ac + 3][ar] = av.w;
    *(float4*)&Bs[brr][bc] = wv;
    __syncthreads();
#pragma unroll
    for (int kk = 0; kk < BKG; kk++) {
      float4 a = *(const float4*)&As[kk][ty * 4];
      float4 b = *(const float4*)&Bs[kk][tx * 4];
      float aa[4] = {a.x, a.y, a.z, a.w};
      float bb[4] = {b.x, b.y, b.z, b.w};
#pragma unroll
      for (int i = 0; i < 4; i++)
#pragma unroll
        for (int j = 0; j < 4; j++) acc[i][j] += aa[i] * bb[j];
    }
    __syncthreads();
  }
  float4 bv = *(const float4*)&bias[n0 + tx * 4];
  float bb[4] = {bv.x, bv.y, bv.z, bv.w};
#pragma unroll
  for (int i = 0; i < 4; i++) {
    float4 o;
    o.x = acc[i][0] + bb[0];
    o.y = acc[i][1] + bb[1];
    o.z = acc[i][2] + bb[2];
    o.w = acc[i][3] + bb[3];
    *(float4*)&C[(size_t)(m0 + ty * 4 + i) * ldc + n0 + tx * 4] = o;
  }
}

// ---------------------------------------------------------------------------
// bf16 MFMA GEMM: C[M,N] = A[M,K] @ BT[N,K]^T + bias, fp32 accumulate.
// 128x128 tile, BK=64, 4 waves, 16x16x32 MFMA, 4x4 acc tiles per wave.
// LDS is FRAGMENT-MAJOR: chunk ch=(mt*2+kk) holds lane l's 8 bf16
// A[m0+mt*16+(l&15)][k0+kk*32+(l>>4)*8 .. +7] at offset ch*1024 + l*16 —
// so global_load_lds (wave-uniform base + lane*16) stages it directly and
// the MFMA fragment read is ONE conflict-free ds_read_b128 per tile.
// ---------------------------------------------------------------------------
__global__ __launch_bounds__(256) void mfma_gemm_bt(
    const unsigned short* __restrict__ A,   // [M,K] bf16
    const unsigned short* __restrict__ BT,  // [N,K] bf16
    const float* __restrict__ bias,         // [N]
    float* __restrict__ C,                  // [M,N] fp32
    int M, int N, int K) {
  __shared__ bf16x8 lA[16][64];  // 16 KB
  __shared__ bf16x8 lB[16][64];  // 16 KB
  int tid = threadIdx.x;
  int w = tid >> 6, lane = tid & 63;
  int m0 = blockIdx.y * 128, n0 = blockIdx.x * 128;
  int wm = w >> 1, wn = w & 1;
  f32x4 acc[4][4] = {};
  int sr = lane & 15;              // row within 16-row tile
  int sk = (lane >> 4) * 8;        // k offset within 32-k step
  const unsigned short* Abase = A + (size_t)(m0 + sr) * K + sk;
  const unsigned short* Bbase = BT + (size_t)(n0 + sr) * K + sk;

  for (int k0 = 0; k0 < K; k0 += 64) {
    __syncthreads();               // previous iter's reads done
#pragma unroll
    for (int c = 0; c < 4; c++) {
      int ch = w * 4 + c;          // chunk 0..15 = (tile<<1)|kk
      int tt = ch >> 1, kk = ch & 1;
      gload_lds16(Abase + (size_t)(tt * 16) * K + k0 + kk * 32, &lA[ch][0]);
      gload_lds16(Bbase + (size_t)(tt * 16) * K + k0 + kk * 32, &lB[ch][0]);
    }
    __syncthreads();               // drains vmcnt (global_load_lds) too
#pragma unroll
    for (int kk = 0; kk < 2; kk++) {
      bf16x8 af[4], bfr[4];
#pragma unroll
      for (int t = 0; t < 4; t++) {
        af[t]  = lA[(wm * 4 + t) * 2 + kk][lane];
        bfr[t] = lB[(wn * 4 + t) * 2 + kk][lane];
      }
#pragma unroll
      for (int i = 0; i < 4; i++)
#pragma unroll
        for (int j = 0; j < 4; j++)
          acc[i][j] = __builtin_amdgcn_mfma_f32_16x16x32_bf16(
              af[i], bfr[j], acc[i][j], 0, 0, 0);
    }
  }
  // C/D layout: col=lane&15, row=(lane>>4)*4+reg  [verified m89/m91]
  int col0 = n0 + wn * 64 + (lane & 15);
  int row0 = m0 + wm * 64 + (lane >> 4) * 4;
#pragma unroll
  for (int j = 0; j < 4; j++) {
    float bv = bias[col0 + j * 16];
#pragma unroll
    for (int i = 0; i < 4; i++) {
#pragma unroll
      for (int r = 0; r < 4; r++)
        C[(size_t)(row0 + i * 16 + r) * N + col0 + j * 16] = acc[i][j][r] + bv;
    }
  }
}

// ---------------------------------------------------------------------------
// fp32 -> bf16 flat convert (RNE), 4 elems/thread.
// ---------------------------------------------------------------------------
__global__ __launch_bounds__(256) void convert_bf16_kernel(
    const float* __restrict__ X, unsigned short* __restrict__ Y, int n4) {
  int i = blockIdx.x * 256 + threadIdx.x;
  if (i >= n4) return;
  float4 v = ((const float4*)X)[i];
  ushort4 o;
  o.x = bf16rne(v.x); o.y = bf16rne(v.y);
  o.z = bf16rne(v.z); o.w = bf16rne(v.w);
  ((ushort4*)Y)[i] = o;
}

// ---------------------------------------------------------------------------
// fp32 [K,N] -> bf16 [N,K] transpose-convert, 32x32 LDS tile.
// ---------------------------------------------------------------------------
__global__ __launch_bounds__(256) void transpose_bf16_kernel(
    const float* __restrict__ W, unsigned short* __restrict__ WT,
    int K, int N) {
  __shared__ unsigned short t[32][33];
  int k0 = blockIdx.y * 32, n0 = blockIdx.x * 32;
  int tid = threadIdx.x;
#pragma unroll
  for (int i = 0; i < 4; i++) {
    int idx = tid + i * 256;
    int r = idx >> 5, c = idx & 31;
    t[c][r] = bf16rne(W[(size_t)(k0 + r) * N + n0 + c]);
  }
  __syncthreads();
#pragma unroll
  for (int i = 0; i < 4; i++) {
    int idx = tid + i * 256;
    int r = idx >> 5, c = idx & 31;
    WT[(size_t)(n0 + r) * K + k0 + c] = t[r][c];
  }
}

// ---------------------------------------------------------------------------
// Selection v2: block = 4 rows, 4 waves. Phase 1: scores into LDS (all 256
// threads). Phase 2: wave wv owns row wv — iterative top-64 via butterfly
// shfl_xor max over encoded (value, ~index) keys; winner's owner lane
// invalidates in LDS and rescans. NO per-iteration barriers.
// Tie-break matches jax.lax.top_k: larger value, then smaller index.
// ---------------------------------------------------------------------------
__device__ inline unsigned long long sel_encode(float v, int c) {
  unsigned u = __float_as_uint(v);
  u = (u & 0x80000000u) ? ~u : (u | 0x80000000u);
  return ((unsigned long long)u << 32) | (unsigned)(0xFFFFFFFFu - (unsigned)c);
}

__global__ __launch_bounds__(256) void select_topk_kernel(
    const float* __restrict__ qsel,   // [BT,128] fp32, head 0 (normed+roped)
    const float* __restrict__ kv,     // [BT,1024] fp32
    int* __restrict__ sel_cnt, int* __restrict__ sel_idx) {
  int blk = blockIdx.x;            // B*T/4 blocks
  int b = blk >> 9;
  int r0 = (blk & 511) * 4;
  int tid = threadIdx.x;

  if (r0 < 64) {                   // rows 0..63: all causal keys selected
    for (int j = 0; j < 4; j++) {
      int r = r0 + j;
      int row = b * T_SEQ + r;
      if (tid == 0) sel_cnt[row] = r + 1;
      for (int c = tid; c <= r; c += 256) sel_idx[row * 66 + c] = c;
    }
    return;
  }

  __shared__ float qs[4][64];
  __shared__ float sc[4][2048];
  __shared__ int winsh[4][65];

  {
    int j = tid >> 6, d = tid & 63;
    qs[j][d] = qsel[(size_t)(b * T_SEQ + r0 + j) * 128 + d];
  }
  __syncthreads();

  // scores (sequential d-order => bit-identical to round 1)
  for (int k8 = 0; k8 < 8; k8++) {
    int c = tid + 256 * k8;
    const float* kp = kv + (size_t)(b * T_SEQ + c) * 1024;
    float a0 = 0.f, a1 = 0.f, a2 = 0.f, a3 = 0.f;
    for (int dd = 0; dd < 64; dd += 16) {
      float kreg[16];
#pragma unroll
      for (int i = 0; i < 4; i++)
        *(float4*)&kreg[i * 4] = *(const float4*)(kp + dd + i * 4);
#pragma unroll
      for (int i = 0; i < 16; i++) {
        float kvv = kreg[i];
        a0 += qs[0][dd + i] * kvv;
        a1 += qs[1][dd + i] * kvv;
        a2 += qs[2][dd + i] * kvv;
        a3 += qs[3][dd + i] * kvv;
      }
    }
    sc[0][c] = (c <= r0 + 0) ? a0 * 0.125f : -INFINITY;
    sc[1][c] = (c <= r0 + 1) ? a1 * 0.125f : -INFINITY;
    sc[2][c] = (c <= r0 + 2) ? a2 * 0.125f : -INFINITY;
    sc[3][c] = (c <= r0 + 3) ? a3 * 0.125f : -INFINITY;
  }
  __syncthreads();

  int wv = tid >> 6, lane = tid & 63;
  int rr = r0 + wv;

  unsigned long long lb = 0ull;
#pragma unroll
  for (int i = 0; i < 32; i++) {
    int c = i * 64 + lane;
    unsigned long long e = sel_encode(sc[wv][c], c);
    lb = lb > e ? lb : e;
  }
  for (int it = 0; it < 64; it++) {
    unsigned long long wb = lb;
#pragma unroll
    for (int off = 1; off < 64; off <<= 1) {
      unsigned long long o = __shfl_xor(wb, off);
      wb = wb > o ? wb : o;
    }
    int c = (int)(0xFFFFFFFFu - (unsigned)(wb & 0xFFFFFFFFull));
    if (lane == 0) winsh[wv][it] = c;
    if ((c & 63) == lane) {        // owner invalidates + rescans its 32
      sc[wv][c] = -INFINITY;
      unsigned long long nb = 0ull;
#pragma unroll
      for (int i = 0; i < 32; i++) {
        int cc = i * 64 + lane;
        unsigned long long e = sel_encode(sc[wv][cc], cc);
        nb = nb > e ? nb : e;
      }
      lb = nb;
    }
  }
  int row = b * T_SEQ + rr;
  unsigned long long bal = __ballot(winsh[wv][lane] == rr);
  int cnt = 64;
  if (bal == 0ull) cnt = 65;
  if (lane == 0) {
    sel_cnt[row] = cnt;
    if (cnt == 65) sel_idx[row * 66 + 64] = rr;
  }
  sel_idx[row * 66 + lane] = winsh[wv][lane];
}

// ---------------------------------------------------------------------------
// Gathered attention (unchanged from round 1 — passed).
// ---------------------------------------------------------------------------
__global__ __launch_bounds__(256) void attn_kernel(
    const float* __restrict__ q, const float* __restrict__ kv,
    const int* __restrict__ sel_cnt, const int* __restrict__ sel_idx,
    float* __restrict__ yg) {
  int blk = blockIdx.x;
  int g = blk & 3;
  int br = blk >> 2;
  int b = br >> 11;
  int r = br & (T_SEQ - 1);
  int tid = threadIdx.x;
  int lane = tid & 63, wv = tid >> 6;

  __shared__ float ksT[128][67];
  __shared__ float qsh[4][128];
  __shared__ int idxs[66];

  int cnt = sel_cnt[br];
  if (tid < cnt) idxs[tid] = sel_idx[br * 66 + tid];
  for (int i = tid; i < 4 * 128; i += 256) {
    int h = i >> 7, d = i & 127;
    qsh[h][d] = q[((size_t)br * NHEADS + g * 4 + h) * HD + d];
  }
  __syncthreads();
  for (int i = tid; i < cnt * 32; i += 256) {
    int j = i >> 5, d4 = (i & 31) * 4;
    const float* kp = kv + (size_t)(b * T_SEQ + idxs[j]) * 1024 + g * HD + d4;
    float4 kd = *(const float4*)kp;
    ksT[d4 + 0][j] = kd.x; ksT[d4 + 1][j] = kd.y;
    ksT[d4 + 2][j] = kd.z; ksT[d4 + 3][j] = kd.w;
  }
  __syncthreads();

  int H = g * 4 + wv;
  double sd = 1.0;
  for (int i = 0; i <= H; i++) sd *= 0.70710678118654752440;
  float slope = (float)sd;

  float s0 = -INFINITY, s1 = -INFINITY;
  for (int jj = lane; jj < cnt; jj += 64) {
    float acc = 0.f;
#pragma unroll 8
    for (int d = 0; d < 128; d++) acc += qsh[wv][d] * ksT[d][jj];
    float sca = acc / sqrtf(128.0f);
    float tch = tanhf(sca / 30.0f) * 30.0f;
    float biasv = -slope * (float)(r - idxs[jj]);
    float val = tch + biasv;
    if (jj == lane) s0 = val; else s1 = val;
  }
  float m = fmaxf(s0, s1);
#pragma unroll
  for (int off = 32; off > 0; off >>= 1) m = fmaxf(m, __shfl_down(m, off));
  m = __shfl(m, 0);
  float e0 = (lane < cnt) ? expf(s0 - m) : 0.f;
  float e1 = (lane + 64 < cnt) ? expf(s1 - m) : 0.f;
  float sum = e0 + e1;
#pragma unroll
  for (int off = 32; off > 0; off >>= 1) sum += __shfl_down(sum, off);
  sum = __shfl(sum, 0);
  float p0 = e0 / sum;
  float p1 = e1 / sum;

  const float* vbase = kv + (size_t)b * T_SEQ * 1024 + 512 + g * HD;
  float y0 = 0.f, y1 = 0.f;
  for (int j = 0; j < cnt; j++) {
    float pj = (j < 64) ? __shfl(p0, j) : __shfl(p1, j - 64);
    const float* vp = vbase + (size_t)idxs[j] * 1024;
    y0 += pj * vp[lane];
    y1 += pj * vp[lane + 64];
  }
  float* op = yg + (size_t)br * 2048 + H * HD;
  op[lane] = y0;
  op[lane + 64] = y1;
}

// ---------------------------------------------------------------------------
// Gate (unchanged from round 1).
// ---------------------------------------------------------------------------
__global__ __launch_bounds__(256) void gate_kernel(
    float* __restrict__ yg, const float* __restrict__ gw,
    const float* __restrict__ gb) {
  int blk = blockIdx.x;
  int h = blk & 15;
  int bt0 = (blk >> 4) * 16;
  int tid = threadIdx.x;
  __shared__ float ys[16][128];
  for (int i = tid; i < 16 * 128; i += 256) {
    int rr = i >> 7, d = i & 127;
    ys[rr][d] = yg[(size_t)(bt0 + rr) * 2048 + h * HD + d];
  }
  __syncthreads();
  int e = tid & 127;
  int rblk = tid >> 7;
  const float* gwp = gw + (size_t)h * 16384 + e;
  float acc[8] = {};
  for (int d = 0; d < 128; d++) {
    float wval = gwp[(size_t)d * 128];
#pragma unroll
    for (int k = 0; k < 8; k++) acc[k] += ys[rblk * 8 + k][d] * wval;
  }
  float bb = gb[h * 128 + e];
#pragma unroll
  for (int k = 0; k < 8; k++) {
    int rr = rblk * 8 + k;
    float gate = 1.f / (1.f + expf(-(acc[k] + bb)));
    yg[(size_t)(bt0 + rr) * 2048 + h * HD + e] = ys[rr][e] * gate;
  }
}

// ---------------------------------------------------------------------------
extern "C" void kernel_launch(void* const* d_in, const int* in_sizes, int n_in,
                              void* d_out, int out_size, void* d_ws, size_t ws_size,
                              hipStream_t stream) {
  const float* x      = (const float*)d_in[0];
  const float* w_q    = (const float*)d_in[1];
  const float* b_q    = (const float*)d_in[2];
  const float* w_down = (const float*)d_in[3];
  const float* b_down = (const float*)d_in[4];
  const float* w_up   = (const float*)d_in[5];
  const float* b_up   = (const float*)d_in[6];
  const float* w_o    = (const float*)d_in[7];
  const float* b_o    = (const float*)d_in[8];
  const float* qn_w   = (const float*)d_in[9];
  const float* kn_w   = (const float*)d_in[10];
  const float* gate_w = (const float*)d_in[11];
  const float* gate_b = (const float*)d_in[12];

  // ws layout:
  // [floats] kv 4.19M | yg 8.39M (dlat aliases head) | tab 262K | cnt/sidx
  //          ~275K ints | qsel 524K
  // [bf16/ushort, after] xb 8.39M (ygb aliases) | wT 4.19M   (~80 MB total)
  float* ws    = (float*)d_ws;
  float* kvbuf = ws;
  float* yg    = ws + 4194304;
  float* dlat  = yg;                          // dead before attn writes yg
  float* tab   = ws + 12582912;
  int*   cnt   = (int*)(ws + 12845056);
  int*   sidx  = cnt + 4096;
  float* qsel  = ws + 13120000;               // 4096 x 128
  unsigned short* xb  = (unsigned short*)(ws + 13644288);  // 4096x2048 bf16
  unsigned short* ygb = xb;                   // xb dead after q-proj
  unsigned short* wT  = xb + 8388608;         // 2048x2048 bf16 [N,K]

  float* qbuf = (float*)d_out;                // d_out doubles as q staging
  const int BT = BATCH * T_SEQ;               // 4096

  rope_table_kernel<<<T_SEQ, 64, 0, stream>>>(tab);
  // bf16 staging for q-proj
  convert_bf16_kernel<<<8192, 256, 0, stream>>>(x, xb, 2097152);
  transpose_bf16_kernel<<<dim3(64, 64), 256, 0, stream>>>(w_q, wT, 2048, 2048);
  // q = x @ w_q + b_q  (bf16 MFMA, fp32 out -> d_out)
  mfma_gemm_bt<<<dim3(16, 32), 256, 0, stream>>>(xb, wT, b_q, qbuf,
                                                 BT, 2048, 2048);
  // exact fp32 selection q: head 0 (cols 0..127)
  sgemm_kernel<<<dim3(2, 64), 256, 0, stream>>>(x, w_q, b_q, qsel,
                                                BT, 128, 2048, 2048, 128);
  // latent path fp32 (feeds selection k exactly)
  sgemm_kernel<<<dim3(8, 64), 256, 0, stream>>>(x, w_down, b_down, dlat,
                                                BT, 512, 2048, 512, 512);
  sgemm_kernel<<<dim3(16, 64), 256, 0, stream>>>(dlat, w_up, b_up, kvbuf,
                                                 BT, 1024, 512, 1024, 1024);
  // rmsnorm + rope
  norm_rope_kernel<<<BT * 16, 128, 0, stream>>>(qbuf, qn_w, tab, 16, 2048);
  norm_rope_kernel<<<BT, 128, 0, stream>>>(qsel, qn_w, tab, 1, 128);
  norm_rope_kernel<<<BT * 4, 128, 0, stream>>>(kvbuf, kn_w, tab, 4, 1024);
  // top-64 selection (fp32-exact path)
  select_topk_kernel<<<BT / 4, 256, 0, stream>>>(qsel, kvbuf, cnt, sidx);
  // gathered sparse attention -> yg
  attn_kernel<<<BT * 4, 256, 0, stream>>>(qbuf, kvbuf, cnt, sidx, yg);
  // per-head gating, in place
  gate_kernel<<<(BT / 16) * 16, 256, 0, stream>>>(yg, gate_w, gate_b);
  // o-proj: bf16 MFMA
  convert_bf16_kernel<<<8192, 256, 0, stream>>>(yg, ygb, 2097152);
  transpose_bf16_kernel<<<dim3(64, 64), 256, 0, stream>>>(w_o, wT, 2048, 2048);
  mfma_gemm_bt<<<dim3(16, 32), 256, 0, stream>>>(ygb, wT, b_o, (float*)d_out,
                                                 BT, 2048, 2048);
}